// Round 5
// baseline (76.073 us; speedup 1.0000x reference)
//
#include <hip/hip_runtime.h>
#include <hip/hip_bf16.h>

// MiniBatchDiscrimination via bf16 MFMA (gfx950) -- SINGLE kernel, no pack_T.
// x: [32,16,16,256] f32, T: [256,64,8] f32, out: [32,16,16,320] f32.
//
// R5 rationale: R1/R3/R4 internal mbd changes were all ~neutral while R2
// (single-kernel, spilled) cost +58us -> consistent accounting: fixed harness
// overhead ~70us (256MB ws fill ~41us unconditional + out fill + restores +
// ~4-5us per dispatch-node gap), mbd itself only ~4-6us. Only lever left:
// fewer dispatches. This round folds pack_T into mbd WITHOUT R2's spill:
//   - B streamed per-kt straight from T (L2-hot), raw f32 in regs with +1-kt
//     prefetch, packed to bf16 right before MFMA (bit-identical to pack_T).
//   - Phase 3b remapped (b=tid&15, i=tid>>4) -> o_b stores directly coalesced
//     (64B per 16-lane group); obuf transpose + 1 barrier + phase 3c removed.
//   - launch_bounds(256,4): VGPR cap 128, ~70-90 live -> no scratch.

namespace {
constexpr int kN = 32;
constexpr int kHW = 256;
constexpr int kF = 256;          // GEMM K
constexpr int kOutRow = 320;
constexpr int kMstride = 136;    // ushorts/row: 128 + 8 pad (272 B, 16B-aligned)
}

using frag_ab = __attribute__((ext_vector_type(8))) short;   // 8 bf16
using frag_cd = __attribute__((ext_vector_type(4))) float;   // 4 f32
typedef _Float16 h2 __attribute__((ext_vector_type(2)));     // packed f16 pair

__device__ inline unsigned short f2bf(float f) {
  union { __hip_bfloat16 h; unsigned short u; } c;
  c.h = __float2bfloat16(f);
  return c.u;
}

__device__ inline unsigned pk2(float a, float b) {
  return (unsigned)f2bf(a) | ((unsigned)f2bf(b) << 16);
}

// |a-b| over a packed f16 pair: v_pk_add_f16(neg) + v_and_b32 (clears both signs)
__device__ inline h2 absd2(unsigned a, unsigned b) {
  h2 d = __builtin_bit_cast(h2, a) - __builtin_bit_cast(h2, b);
  return __builtin_bit_cast(h2, __builtin_bit_cast(unsigned, d) & 0x7fff7fffu);
}

// L1 distance over 8 c's held as 4 packed-f16 dwords.
__device__ inline float l1_8(const uint4& a, const uint4& b) {
  h2 s01 = absd2(a.x, b.x) + absd2(a.y, b.y);
  h2 s23 = absd2(a.z, b.z) + absd2(a.w, b.w);
  h2 s = s01 + s23;
  return (float)s.x + (float)s.y;
}

// ---- Fused kernel: 256 threads, one t-quarter per block, grid 1024 ----
__global__ __launch_bounds__(256, 4)
void mbd_main(const float* __restrict__ x, const float* __restrict__ T,
              float* __restrict__ out) {
  __shared__ uint4 Afrag[2 * 8 * 64];                           // 16 KB
  __shared__ __align__(16) unsigned short Mlds[kN * kMstride];  // 8.7 KB (f16)
  const int hw = blockIdx.x & (kHW - 1);
  const int qg = blockIdx.x >> 8;          // t-quarter 0..3 (16 b's, 128 t-cols)
  const int tid = threadIdx.x;
  const int l = tid & 63, w = tid >> 6;    // 4 waves; wave owns t-tiles {2w,2w+1}

  // Phase 0: preload kt=0 B-columns raw f32 (L2-hot; latency hides under ph.1).
  // Lane l, t-tile tT=qg*8+w*2(+q): col = tT*16 + (l&15); rows (l>>4)*8 + j.
  // Bit-identical to old pack_T (same loads, same f2bf rounding at pack time).
  const float* tb = T + (size_t)((l >> 4) * 8) * 512
                      + (qg * 8 + w * 2) * 16 + (l & 15);
  float c0[8], c1[8];
#pragma unroll
  for (int j = 0; j < 8; ++j) { c0[j] = tb[j * 512]; c1[j] = tb[j * 512 + 16]; }

  // Phase 1: stage x -> A-frags (bf16) + passthrough this quarter's features.
  const float4* x4 = (const float4*)x;
  float4* out4 = (float4*)out;
#pragma unroll
  for (int s = 0; s < 4; ++s) {
    const int task = tid + s * 256;        // 1024 tasks: 32 n x 32 k-groups
    const int n = task >> 5;
    const int k8 = task & 31;              // group of 8 features
    const size_t xb = (size_t)n * (kHW * kF / 4) + (size_t)hw * (kF / 4) + k8 * 2;
    float4 v0 = x4[xb];
    float4 v1 = x4[xb + 1];
    if ((k8 >> 3) == qg) {                 // this block's quarter of features
      const size_t ob = (size_t)(n * kHW + hw) * (kOutRow / 4) + k8 * 2;
      out4[ob] = v0;
      out4[ob + 1] = v1;
    }
    uint4 p;
    p.x = pk2(v0.x, v0.y);
    p.y = pk2(v0.z, v0.w);
    p.z = pk2(v1.x, v1.y);
    p.w = pk2(v1.z, v1.w);
    const int rt = n >> 4, kt = k8 >> 2, ln = (n & 15) | ((k8 & 3) << 4);
    Afrag[(rt * 8 + kt) * 64 + ln] = p;
  }
  __syncthreads();

  // Phase 2: MFMA GEMM; B streamed from T (L2) with +1-kt prefetch, packed
  // to bf16 just before use.
  frag_cd acc[2][2] = {};                  // [q][rt]
  float n0[8], n1[8];
#pragma unroll
  for (int kt = 0; kt < 8; ++kt) {
    if (kt < 7) {
      const float* tn = tb + (size_t)(kt + 1) * (32 * 512);
#pragma unroll
      for (int j = 0; j < 8; ++j) { n0[j] = tn[j * 512]; n1[j] = tn[j * 512 + 16]; }
    }
    uint4 b0 = make_uint4(pk2(c0[0], c0[1]), pk2(c0[2], c0[3]),
                          pk2(c0[4], c0[5]), pk2(c0[6], c0[7]));
    uint4 b1 = make_uint4(pk2(c1[0], c1[1]), pk2(c1[2], c1[3]),
                          pk2(c1[4], c1[5]), pk2(c1[6], c1[7]));
    uint4 a0 = Afrag[(0 * 8 + kt) * 64 + l];
    uint4 a1 = Afrag[(1 * 8 + kt) * 64 + l];
    frag_ab af0 = __builtin_bit_cast(frag_ab, a0);
    frag_ab af1 = __builtin_bit_cast(frag_ab, a1);
    frag_ab bf0 = __builtin_bit_cast(frag_ab, b0);
    frag_ab bf1 = __builtin_bit_cast(frag_ab, b1);
    acc[0][0] = __builtin_amdgcn_mfma_f32_16x16x32_bf16(af0, bf0, acc[0][0], 0, 0, 0);
    acc[0][1] = __builtin_amdgcn_mfma_f32_16x16x32_bf16(af1, bf0, acc[0][1], 0, 0, 0);
    acc[1][0] = __builtin_amdgcn_mfma_f32_16x16x32_bf16(af0, bf1, acc[1][0], 0, 0, 0);
    acc[1][1] = __builtin_amdgcn_mfma_f32_16x16x32_bf16(af1, bf1, acc[1][1], 0, 0, 0);
#pragma unroll
    for (int j = 0; j < 8; ++j) { c0[j] = n0[j]; c1[j] = n1[j]; }
  }

  // Phase 3a: park M quarter as f16. C/D: col = l&15, row = (l>>4)*4 + r.
#pragma unroll
  for (int q = 0; q < 2; ++q)
#pragma unroll
    for (int rt = 0; rt < 2; ++rt)
#pragma unroll
      for (int r = 0; r < 4; ++r) {
        const int n = rt * 16 + (l >> 4) * 4 + r;
        const int t = (w * 2 + q) * 16 + (l & 15);  // local col 0..127
        Mlds[n * kMstride + t] =
            __builtin_bit_cast(unsigned short, (_Float16)acc[q][rt][r]);
      }
  __syncthreads();

  // Phase 3b: pairwise exp(-L1), packed f16. Mapping: b = tid&15 (local b),
  // ip = tid>>4, i in {ip, ip+16}. mi/mj reads: 16 lanes x contiguous 16B
  // (2-way bank alias = free); o_b stores directly coalesced (64B/group) ->
  // no obuf transpose, no extra barrier, no separate store phase.
  const int b = tid & 15;
  const int ip = tid >> 4;                 // 0..15
  const uint4 mi0 = *(const uint4*)&Mlds[ip * kMstride + b * 8];
  const uint4 mi1 = *(const uint4*)&Mlds[(ip + 16) * kMstride + b * 8];
  float ob0 = 0.f, ob1 = 0.f;
#pragma unroll 8
  for (int j = 0; j < kN; ++j) {
    const uint4 mj = *(const uint4*)&Mlds[j * kMstride + b * 8];
    ob0 += __expf(-l1_8(mi0, mj));
    ob1 += __expf(-l1_8(mi1, mj));
  }
  const size_t o0 = (size_t)(ip * kHW + hw) * kOutRow + kF + qg * 16 + b;
  out[o0] = ob0;
  out[o0 + (size_t)16 * kHW * kOutRow] = ob1;   // i = ip + 16
}

extern "C" void kernel_launch(void* const* d_in, const int* in_sizes, int n_in,
                              void* d_out, int out_size, void* d_ws, size_t ws_size,
                              hipStream_t stream) {
  const float* x = (const float*)d_in[0];     // [32,16,16,256]
  const float* T = (const float*)d_in[1];     // [256,64,8] = [256][512]
  float* out = (float*)d_out;                 // [32,16,16,320]
  (void)in_sizes; (void)n_in; (void)out_size; (void)d_ws; (void)ws_size;
  mbd_main<<<dim3(4 * kHW), dim3(256), 0, stream>>>(x, T, out);
}